// Round 3
// baseline (604.823 us; speedup 1.0000x reference)
//
#include <hip/hip_runtime.h>

#define N_TOK 8192
#define D_IN 384
#define D_H 64
#define NHEADS 4
#define NSPLIT 4
#define N_CLS 6
#define LN_EPS 1e-5f

typedef __attribute__((ext_vector_type(8))) short short8;
typedef __attribute__((ext_vector_type(4))) float f32x4;

#define L2E2 2.08136898100560774f   /* (log2 e)^2 */

__device__ __forceinline__ unsigned short f2bf(float f) {
    unsigned int u = __float_as_uint(f);
    u += 0x7FFFu + ((u >> 16) & 1u);          // RNE (finite values only here)
    return (unsigned short)(u >> 16);
}
__device__ __forceinline__ float bf2f(unsigned short s) {
    return __uint_as_float(((unsigned int)s) << 16);
}

// Permuted key position within a 64-key tile (pairs bf16 cols for packed LDS
// writes). P-columns and V-rows use the same bijection -> PV invariant.
__device__ __forceinline__ int kperm(int k) {
    return (k & 32) + 2 * (k & 15) + ((k >> 4) & 1);
}

// ---------------------------------------------------------------------------
// Stage 1: h = relu(x @ proj_w + proj_b); hp[h] = h @ head_w[h] + head_b[h]
// 4 rows per wave (weight loads reused x4 in registers).
// Outputs: hp bf16 [H][N][64] row-major, Vf bf16 key-grouped+permuted for PV
// B-frags, ssq2 fp32 [H][N] = (sum hp^2) * (log2 e)^2  (pre-scaled).
// ---------------------------------------------------------------------------
__global__ __launch_bounds__(256) void stage1_kernel(
    const float* __restrict__ x, const float* __restrict__ proj_w,
    const float* __restrict__ proj_b, const float* __restrict__ head_w,
    const float* __restrict__ head_b,
    unsigned short* __restrict__ hp, unsigned short* __restrict__ Vf,
    float* __restrict__ ssq2)
{
    const int lane = threadIdx.x & 63;
    const int ty   = threadIdx.x >> 6;
    const int rb   = blockIdx.x * 16 + ty * 4;   // 4 rows per wave

    __shared__ float h_sh[4][64][4];             // [wave][feature][row]

    float acc[4];
    {
        float b = proj_b[lane];
        #pragma unroll
        for (int r = 0; r < 4; ++r) acc[r] = b;
    }
    const float* x0 = x + (size_t)rb * D_IN;
    #pragma unroll 2
    for (int k4 = 0; k4 < D_IN / 4; ++k4) {
        float w0 = proj_w[(k4 * 4 + 0) * 64 + lane];
        float w1 = proj_w[(k4 * 4 + 1) * 64 + lane];
        float w2 = proj_w[(k4 * 4 + 2) * 64 + lane];
        float w3 = proj_w[(k4 * 4 + 3) * 64 + lane];
        #pragma unroll
        for (int r = 0; r < 4; ++r) {
            float4 xv = *(const float4*)(x0 + r * D_IN + k4 * 4); // wave-uniform
            acc[r] = fmaf(xv.x, w0, acc[r]);
            acc[r] = fmaf(xv.y, w1, acc[r]);
            acc[r] = fmaf(xv.z, w2, acc[r]);
            acc[r] = fmaf(xv.w, w3, acc[r]);
        }
    }
    #pragma unroll
    for (int r = 0; r < 4; ++r) h_sh[ty][lane][r] = fmaxf(acc[r], 0.f);
    // wave-private LDS segment; in-order DS pipe -> no barrier needed

    #pragma unroll
    for (int hh = 0; hh < NHEADS; ++hh) {
        float a[4];
        {
            float b = head_b[hh * 64 + lane];
            #pragma unroll
            for (int r = 0; r < 4; ++r) a[r] = b;
        }
        const float* wb = head_w + hh * 64 * 64;
        #pragma unroll 4
        for (int e = 0; e < 64; ++e) {
            float wv = wb[e * 64 + lane];
            float4 hv = *(const float4*)&h_sh[ty][e][0];   // uniform -> broadcast
            a[0] = fmaf(hv.x, wv, a[0]);
            a[1] = fmaf(hv.y, wv, a[1]);
            a[2] = fmaf(hv.z, wv, a[2]);
            a[3] = fmaf(hv.w, wv, a[3]);
        }
        #pragma unroll
        for (int r = 0; r < 4; ++r) {
            int row = rb + r;
            unsigned short hb = f2bf(a[r]);
            float hf = bf2f(hb);
            hp[(hh * N_TOK + row) * 64 + lane] = hb;
            int p = kperm(row & 63);
            Vf[((hh * (N_TOK / 8) + ((row >> 6) << 3) + (p >> 3)) * 64 + lane) * 8
               + (p & 7)] = hb;
            float s = hf * hf;
            #pragma unroll
            for (int off = 32; off > 0; off >>= 1) s += __shfl_xor(s, off);
            if (lane == 0) ssq2[hh * N_TOK + row] = s * L2E2;
        }
    }
}

// ---------------------------------------------------------------------------
// Flash distance-attention. Grid (16 head/split combos, 128 q-tiles); combo
// lands on XCD combo&7 -> <=2 heads per XCD (~1 MB L2 working set).
// 4 K-splits x 4 heads x 512 q-waves = 8192 waves = 8 waves/SIMD (the round-2
// kernel had 4/SIMD and was latency-bound: all pipes <25% busy).
// __launch_bounds__(256,8) pins VGPR<=64 so 8 waves/SIMD are resident.
// Wave w owns query rows q0+16w..+15. Max logit is 0 (diagonal) -> no online
// rescaling. p = exp2(-sqrt(sq * (log2 e)^2)); partial O stored in bf16.
// ---------------------------------------------------------------------------
__global__ __launch_bounds__(256, 8) void flash_kernel(
    const unsigned short* __restrict__ hp, const unsigned short* __restrict__ Vf,
    const float* __restrict__ ssq2, unsigned short* __restrict__ Og,
    float* __restrict__ Lg)
{
    const int head  = blockIdx.x >> 2;       // combo = head*4+split
    const int split = blockIdx.x & 3;
    const int qt    = blockIdx.y;            // 0..127
    const int q0    = qt * 64;
    const int w     = threadIdx.x >> 6;
    const int lane  = threadIdx.x & 63;
    const int col   = lane & 15;
    const int quad  = lane >> 4;

    // Per-wave P tile, 16 rows x 64 (permuted) cols, pitch 72 shorts.
    __shared__ __align__(16) unsigned short Psh[4][16][72];

    const unsigned short* hpH = hp + head * (N_TOK * 64);
    const unsigned short* VfH = Vf + head * (N_TOK * 64);
    const float* ssqH = ssq2 + head * N_TOK;

    short8 aQ[2];
    {
        const unsigned short* qrow = hpH + (q0 + w * 16 + col) * 64;
        aQ[0] = *(const short8*)(qrow + quad * 8);
        aQ[1] = *(const short8*)(qrow + 32 + quad * 8);
    }
    float ssqn2[4];
    #pragma unroll
    for (int r = 0; r < 4; ++r)
        ssqn2[r] = ssqH[q0 + w * 16 + quad * 4 + r];

    const f32x4 zero4 = {0.f, 0.f, 0.f, 0.f};
    f32x4 accO[4] = {zero4, zero4, zero4, zero4};
    f32x4 accL = zero4;
    const short8 ones = {16256,16256,16256,16256,16256,16256,16256,16256}; // bf16 1.0
    const float NEG2L2 = -2.0f * L2E2;

    const int kt0 = split * (N_TOK / 64 / NSPLIT);
    #pragma unroll 1
    for (int kt = kt0; kt < kt0 + N_TOK / 64 / NSPLIT; ++kt) {
        const unsigned short* kb = hpH + kt * 4096;
        const unsigned short* vb = VfH + kt * 4096;

        // key sum-squares (pre-scaled), prefetched
        float sm2[4];
        #pragma unroll
        for (int nt = 0; nt < 4; ++nt) sm2[nt] = ssqH[kt * 64 + nt * 16 + col];

        // V fragments (independent of S -> early issue)
        short8 bV[2][4];
        #pragma unroll
        for (int c = 0; c < 2; ++c)
            #pragma unroll
            for (int dt = 0; dt < 4; ++dt)
                bV[c][dt] = *(const short8*)(vb + ((c * 4 + quad) * 64 + dt * 16 + col) * 8);

        // ---- S = Q.K^T cross terms ----
        f32x4 accS[4] = {zero4, zero4, zero4, zero4};
        #pragma unroll
        for (int nt = 0; nt < 4; ++nt) {
            const unsigned short* kr = kb + (nt * 16 + col) * 64 + quad * 8;
            short8 b0 = *(const short8*)kr;
            short8 b1 = *(const short8*)(kr + 32);
            accS[nt] = __builtin_amdgcn_mfma_f32_16x16x32_bf16(aQ[0], b0, accS[nt], 0, 0, 0);
            accS[nt] = __builtin_amdgcn_mfma_f32_16x16x32_bf16(aQ[1], b1, accS[nt], 0, 0, 0);
        }

        // ---- p = exp2(-sqrt(max(sq',0))) : add, fma, max, sqrt, exp ----
        float pf[4][4];
        #pragma unroll
        for (int nt = 0; nt < 4; ++nt)
            #pragma unroll
            for (int r = 0; r < 4; ++r) {
                float sq = fmaf(accS[nt][r], NEG2L2, ssqn2[r] + sm2[nt]);
                float d2 = __builtin_amdgcn_sqrtf(fmaxf(sq, 0.f));
                pf[nt][r] = __builtin_amdgcn_exp2f(-d2);
            }

        // ---- pack bf16 pairs (v_perm truncation), 8 ds_write_b32 ----
        #pragma unroll
        for (int r = 0; r < 4; ++r) {
            unsigned int d0 = __builtin_amdgcn_perm(__float_as_uint(pf[1][r]),
                                                    __float_as_uint(pf[0][r]), 0x07060302u);
            unsigned int d1 = __builtin_amdgcn_perm(__float_as_uint(pf[3][r]),
                                                    __float_as_uint(pf[2][r]), 0x07060302u);
            int rr = quad * 4 + r;
            *(unsigned int*)&Psh[w][rr][2 * col]      = d0;
            *(unsigned int*)&Psh[w][rr][32 + 2 * col] = d1;
        }
        // diag tile: force p=1.0 exactly (one predicated b16 write, 1/32 tiles)
        if (kt == qt && lane < 16)
            Psh[w][lane][((w & 2) << 4) + 2 * lane + (w & 1)] = 0x3F80;

        // ---- PV: O += P.V, l += rowsum(P). Wave-private LDS, no barrier ----
        #pragma unroll
        for (int c = 0; c < 2; ++c) {
            short8 aP = *(const short8*)&Psh[w][col][c * 32 + quad * 8];
            accL = __builtin_amdgcn_mfma_f32_16x16x32_bf16(aP, ones, accL, 0, 0, 0);
            #pragma unroll
            for (int dt = 0; dt < 4; ++dt)
                accO[dt] = __builtin_amdgcn_mfma_f32_16x16x32_bf16(aP, bV[c][dt], accO[dt], 0, 0, 0);
        }
    }

    // ---- epilogue: unnormalized O (bf16) and l (f32) for this split ----
    unsigned short* og = Og + (size_t)(split * NHEADS + head) * N_TOK * 64;
    float* lg = Lg + (size_t)(split * NHEADS + head) * N_TOK;
    #pragma unroll
    for (int r = 0; r < 4; ++r) {
        int row = q0 + w * 16 + quad * 4 + r;
        #pragma unroll
        for (int dt = 0; dt < 4; ++dt)
            og[row * 64 + dt * 16 + col] = f2bf(accO[dt][r]);
        if (col == 0) lg[row] = accL[r];
    }
}

// ---------------------------------------------------------------------------
// Combine: merge 4 splits, head-softmax mix, layernorm, FC. One wave per row.
// ---------------------------------------------------------------------------
__global__ __launch_bounds__(256) void combine_kernel(
    const unsigned short* __restrict__ Og, const float* __restrict__ Lg,
    const float* __restrict__ attn_w, const float* __restrict__ gamma,
    const float* __restrict__ beta, const float* __restrict__ fc_w,
    const float* __restrict__ fc_b, float* __restrict__ out)
{
    const int lane = threadIdx.x & 63;
    const int ty   = threadIdx.x >> 6;
    const int row  = blockIdx.x * 4 + ty;

    float a0 = attn_w[0], a1 = attn_w[1], a2 = attn_w[2], a3 = attn_w[3];
    float m = fmaxf(fmaxf(a0, a1), fmaxf(a2, a3));
    float e0 = __expf(a0 - m), e1 = __expf(a1 - m), e2 = __expf(a2 - m), e3 = __expf(a3 - m);
    float inv = 1.f / (e0 + e1 + e2 + e3);
    float aw[4] = {e0 * inv, e1 * inv, e2 * inv, e3 * inv};

    float c = 0.f;
    #pragma unroll
    for (int hh = 0; hh < NHEADS; ++hh) {
        float l = 0.f, o = 0.f;
        #pragma unroll
        for (int s = 0; s < NSPLIT; ++s) {
            l += Lg[(s * NHEADS + hh) * N_TOK + row];
            o += bf2f(Og[(size_t)((s * NHEADS + hh) * N_TOK + row) * 64 + lane]);
        }
        c += aw[hh] * o * __builtin_amdgcn_rcpf(l);
    }

    float s = c;
    #pragma unroll
    for (int off = 32; off > 0; off >>= 1) s += __shfl_xor(s, off);
    float mu = s * (1.f / 64.f);
    float d = c - mu;
    float v = d * d;
    #pragma unroll
    for (int off = 32; off > 0; off >>= 1) v += __shfl_xor(v, off);
    float normed = d * rsqrtf(v * (1.f / 64.f) + LN_EPS) * gamma[lane] + beta[lane];

    float lg[N_CLS];
    #pragma unroll
    for (int cc = 0; cc < N_CLS; ++cc) {
        float p = normed * fc_w[lane * N_CLS + cc];
        #pragma unroll
        for (int off = 32; off > 0; off >>= 1) p += __shfl_xor(p, off);
        lg[cc] = p;
    }
    if (lane == 0) {
        #pragma unroll
        for (int cc = 0; cc < N_CLS; ++cc)
            out[row * N_CLS + cc] = lg[cc] + fc_b[cc];
    }
}

// ---------------------------------------------------------------------------
extern "C" void kernel_launch(void* const* d_in, const int* in_sizes, int n_in,
                              void* d_out, int out_size, void* d_ws, size_t ws_size,
                              hipStream_t stream)
{
    const float* x      = (const float*)d_in[0];
    const float* proj_w = (const float*)d_in[1];
    const float* proj_b = (const float*)d_in[2];
    const float* head_w = (const float*)d_in[3];
    const float* head_b = (const float*)d_in[4];
    const float* attn_w = (const float*)d_in[5];
    const float* gamma  = (const float*)d_in[6];
    const float* beta   = (const float*)d_in[7];
    const float* fc_w   = (const float*)d_in[8];
    const float* fc_b   = (const float*)d_in[9];
    float* out = (float*)d_out;

    char* ws = (char*)d_ws;
    // ws layout (bytes):
    //   hp   bf16 [4][8192][64]        @ 0        (4 MB)
    //   Vf   bf16 [4][1024][64][8]     @ 4 MB     (4 MB, key-permuted)
    //   ssq2 f32  [4][8192]            @ 8 MB     (128 KB)
    //   Og   bf16 [4][4][8192][64]     @ 8M+128K  (16 MB)
    //   Lg   f32  [4][4][8192]         @ 24M+128K (512 KB)
    unsigned short* hp = (unsigned short*)(ws);
    unsigned short* Vf = (unsigned short*)(ws + (4u << 20));
    float* ssq2 = (float*)(ws + (8u << 20));
    unsigned short* Og = (unsigned short*)(ws + (8u << 20) + (128u << 10));
    float* Lg   = (float*)(ws + (24u << 20) + (128u << 10));

    stage1_kernel<<<N_TOK / 16, 256, 0, stream>>>(x, proj_w, proj_b, head_w, head_b,
                                                  hp, Vf, ssq2);
    dim3 g2(NHEADS * NSPLIT, N_TOK / 64);  // combo fastest -> spread over XCDs
    flash_kernel<<<g2, 256, 0, stream>>>(hp, Vf, ssq2, Og, Lg);
    combine_kernel<<<N_TOK / 4, 256, 0, stream>>>(Og, Lg, attn_w, gamma, beta,
                                                  fc_w, fc_b, out);
}

// Round 4
// 428.570 us; speedup vs baseline: 1.4113x; 1.4113x over previous
//
#include <hip/hip_runtime.h>

#define N_TOK 8192
#define D_IN 384
#define D_H 64
#define NHEADS 4
#define NSPLIT 4
#define N_CLS 6
#define LN_EPS 1e-5f

typedef __attribute__((ext_vector_type(8))) short short8;
typedef __attribute__((ext_vector_type(4))) float f32x4;

#define L2E2 2.08136898100560774f   /* (log2 e)^2 */

__device__ __forceinline__ unsigned short f2bf(float f) {
    unsigned int u = __float_as_uint(f);
    u += 0x7FFFu + ((u >> 16) & 1u);          // RNE (finite values only here)
    return (unsigned short)(u >> 16);
}
__device__ __forceinline__ float bf2f(unsigned short s) {
    return __uint_as_float(((unsigned int)s) << 16);
}

// Permuted key position within a 64-key tile (pairs bf16 cols for packed LDS
// writes). P-columns and V-rows use the same bijection -> PV invariant.
__device__ __forceinline__ int kperm(int k) {
    return (k & 32) + 2 * (k & 15) + ((k >> 4) & 1);
}

// ---------------------------------------------------------------------------
// Stage 1: h = relu(x @ proj_w + proj_b); hp[h] = h @ head_w[h] + head_b[h]
// 4 rows per wave (weight loads reused x4 in registers).
// Outputs: hp bf16 [H][N][64] row-major, Vf bf16 key-grouped+permuted for PV
// B-frags, ssq2 fp32 [H][N] = (sum hp^2) * (log2 e)^2  (pre-scaled).
// ---------------------------------------------------------------------------
__global__ __launch_bounds__(256) void stage1_kernel(
    const float* __restrict__ x, const float* __restrict__ proj_w,
    const float* __restrict__ proj_b, const float* __restrict__ head_w,
    const float* __restrict__ head_b,
    unsigned short* __restrict__ hp, unsigned short* __restrict__ Vf,
    float* __restrict__ ssq2)
{
    const int lane = threadIdx.x & 63;
    const int ty   = threadIdx.x >> 6;
    const int rb   = blockIdx.x * 16 + ty * 4;   // 4 rows per wave

    __shared__ float h_sh[4][64][4];             // [wave][feature][row]

    float acc[4];
    {
        float b = proj_b[lane];
        #pragma unroll
        for (int r = 0; r < 4; ++r) acc[r] = b;
    }
    const float* x0 = x + (size_t)rb * D_IN;
    #pragma unroll 2
    for (int k4 = 0; k4 < D_IN / 4; ++k4) {
        float w0 = proj_w[(k4 * 4 + 0) * 64 + lane];
        float w1 = proj_w[(k4 * 4 + 1) * 64 + lane];
        float w2 = proj_w[(k4 * 4 + 2) * 64 + lane];
        float w3 = proj_w[(k4 * 4 + 3) * 64 + lane];
        #pragma unroll
        for (int r = 0; r < 4; ++r) {
            float4 xv = *(const float4*)(x0 + r * D_IN + k4 * 4); // wave-uniform
            acc[r] = fmaf(xv.x, w0, acc[r]);
            acc[r] = fmaf(xv.y, w1, acc[r]);
            acc[r] = fmaf(xv.z, w2, acc[r]);
            acc[r] = fmaf(xv.w, w3, acc[r]);
        }
    }
    #pragma unroll
    for (int r = 0; r < 4; ++r) h_sh[ty][lane][r] = fmaxf(acc[r], 0.f);
    // wave-private LDS segment; in-order DS pipe -> no barrier needed

    #pragma unroll
    for (int hh = 0; hh < NHEADS; ++hh) {
        float a[4];
        {
            float b = head_b[hh * 64 + lane];
            #pragma unroll
            for (int r = 0; r < 4; ++r) a[r] = b;
        }
        const float* wb = head_w + hh * 64 * 64;
        #pragma unroll 4
        for (int e = 0; e < 64; ++e) {
            float wv = wb[e * 64 + lane];
            float4 hv = *(const float4*)&h_sh[ty][e][0];   // uniform -> broadcast
            a[0] = fmaf(hv.x, wv, a[0]);
            a[1] = fmaf(hv.y, wv, a[1]);
            a[2] = fmaf(hv.z, wv, a[2]);
            a[3] = fmaf(hv.w, wv, a[3]);
        }
        #pragma unroll
        for (int r = 0; r < 4; ++r) {
            int row = rb + r;
            unsigned short hb = f2bf(a[r]);
            float hf = bf2f(hb);
            hp[(hh * N_TOK + row) * 64 + lane] = hb;
            int p = kperm(row & 63);
            Vf[((hh * (N_TOK / 8) + ((row >> 6) << 3) + (p >> 3)) * 64 + lane) * 8
               + (p & 7)] = hb;
            float s = hf * hf;
            #pragma unroll
            for (int off = 32; off > 0; off >>= 1) s += __shfl_xor(s, off);
            if (lane == 0) ssq2[hh * N_TOK + row] = s * L2E2;
        }
    }
}

// ---------------------------------------------------------------------------
// Flash distance-attention. Grid (16 combos, 128 q-tiles), combo =
// split*NHEADS+head so blockIdx.x%8 -> exactly one head per XCD (~2 MB L2 set).
// 4 K-splits give 8192 waves = 8 waves/SIMD wave slots (round-2 was 4/SIMD,
// latency-bound: all pipes <25%). NO min-waves launch-bounds clamp: round 3
// showed (256,8) forces VGPR=32 -> scratch spills (525 MB writes, 1.6x slower).
// Natural VGPR ~60 <= 64 already permits 8 waves/SIMD.
// Wave w owns query rows q0+16w..+15. Max logit is 0 (diagonal) -> no online
// rescaling. p = exp2(-sqrt(sq*(log2 e)^2)); partial O stored bf16.
// ---------------------------------------------------------------------------
__global__ __launch_bounds__(256) void flash_kernel(
    const unsigned short* __restrict__ hp, const unsigned short* __restrict__ Vf,
    const float* __restrict__ ssq2, unsigned short* __restrict__ Og,
    float* __restrict__ Lg)
{
    const int head  = blockIdx.x & 3;        // combo = split*NHEADS+head
    const int split = blockIdx.x >> 2;
    const int qt    = blockIdx.y;            // 0..127
    const int q0    = qt * 64;
    const int w     = threadIdx.x >> 6;
    const int lane  = threadIdx.x & 63;
    const int col   = lane & 15;
    const int quad  = lane >> 4;

    // Per-wave P tile, 16 rows x 64 (permuted) cols, pitch 72 shorts.
    __shared__ __align__(16) unsigned short Psh[4][16][72];

    const unsigned short* hpH = hp + head * (N_TOK * 64);
    const unsigned short* VfH = Vf + head * (N_TOK * 64);
    const float* ssqH = ssq2 + head * N_TOK;

    short8 aQ[2];
    {
        const unsigned short* qrow = hpH + (q0 + w * 16 + col) * 64;
        aQ[0] = *(const short8*)(qrow + quad * 8);
        aQ[1] = *(const short8*)(qrow + 32 + quad * 8);
    }
    float ssqn2[4];
    #pragma unroll
    for (int r = 0; r < 4; ++r)
        ssqn2[r] = ssqH[q0 + w * 16 + quad * 4 + r];

    const f32x4 zero4 = {0.f, 0.f, 0.f, 0.f};
    f32x4 accO[4] = {zero4, zero4, zero4, zero4};
    f32x4 accL = zero4;
    const short8 ones = {16256,16256,16256,16256,16256,16256,16256,16256}; // bf16 1.0
    const float NEG2L2 = -2.0f * L2E2;

    const int kt0 = split * (N_TOK / 64 / NSPLIT);
    #pragma unroll 1
    for (int kt = kt0; kt < kt0 + N_TOK / 64 / NSPLIT; ++kt) {
        const unsigned short* kb = hpH + kt * 4096;
        const unsigned short* vb = VfH + kt * 4096;

        // key sum-squares (pre-scaled), prefetched
        float sm2[4];
        #pragma unroll
        for (int nt = 0; nt < 4; ++nt) sm2[nt] = ssqH[kt * 64 + nt * 16 + col];

        // V fragments (independent of S -> early issue)
        short8 bV[2][4];
        #pragma unroll
        for (int c = 0; c < 2; ++c)
            #pragma unroll
            for (int dt = 0; dt < 4; ++dt)
                bV[c][dt] = *(const short8*)(vb + ((c * 4 + quad) * 64 + dt * 16 + col) * 8);

        // ---- S = Q.K^T cross terms ----
        f32x4 accS[4] = {zero4, zero4, zero4, zero4};
        #pragma unroll
        for (int nt = 0; nt < 4; ++nt) {
            const unsigned short* kr = kb + (nt * 16 + col) * 64 + quad * 8;
            short8 b0 = *(const short8*)kr;
            short8 b1 = *(const short8*)(kr + 32);
            accS[nt] = __builtin_amdgcn_mfma_f32_16x16x32_bf16(aQ[0], b0, accS[nt], 0, 0, 0);
            accS[nt] = __builtin_amdgcn_mfma_f32_16x16x32_bf16(aQ[1], b1, accS[nt], 0, 0, 0);
        }

        // ---- p = exp2(-sqrt(max(sq',0))) : add, fma, max, sqrt, exp ----
        float pf[4][4];
        #pragma unroll
        for (int nt = 0; nt < 4; ++nt)
            #pragma unroll
            for (int r = 0; r < 4; ++r) {
                float sq = fmaf(accS[nt][r], NEG2L2, ssqn2[r] + sm2[nt]);
                float d2 = __builtin_amdgcn_sqrtf(fmaxf(sq, 0.f));
                pf[nt][r] = __builtin_amdgcn_exp2f(-d2);
            }

        // ---- pack bf16 pairs (v_perm truncation), 8 ds_write_b32 ----
        #pragma unroll
        for (int r = 0; r < 4; ++r) {
            unsigned int d0 = __builtin_amdgcn_perm(__float_as_uint(pf[1][r]),
                                                    __float_as_uint(pf[0][r]), 0x07060302u);
            unsigned int d1 = __builtin_amdgcn_perm(__float_as_uint(pf[3][r]),
                                                    __float_as_uint(pf[2][r]), 0x07060302u);
            int rr = quad * 4 + r;
            *(unsigned int*)&Psh[w][rr][2 * col]      = d0;
            *(unsigned int*)&Psh[w][rr][32 + 2 * col] = d1;
        }
        // diag tile: force p=1.0 exactly (one predicated b16 write, 1/32 tiles)
        if (kt == qt && lane < 16)
            Psh[w][lane][((w & 2) << 4) + 2 * lane + (w & 1)] = 0x3F80;

        // ---- PV: O += P.V, l += rowsum(P). Wave-private LDS, no barrier ----
        #pragma unroll
        for (int c = 0; c < 2; ++c) {
            short8 aP = *(const short8*)&Psh[w][col][c * 32 + quad * 8];
            accL = __builtin_amdgcn_mfma_f32_16x16x32_bf16(aP, ones, accL, 0, 0, 0);
            #pragma unroll
            for (int dt = 0; dt < 4; ++dt)
                accO[dt] = __builtin_amdgcn_mfma_f32_16x16x32_bf16(aP, bV[c][dt], accO[dt], 0, 0, 0);
        }
    }

    // ---- epilogue: unnormalized O (bf16) and l (f32) for this split ----
    unsigned short* og = Og + (size_t)(split * NHEADS + head) * N_TOK * 64;
    float* lg = Lg + (size_t)(split * NHEADS + head) * N_TOK;
    #pragma unroll
    for (int r = 0; r < 4; ++r) {
        int row = q0 + w * 16 + quad * 4 + r;
        #pragma unroll
        for (int dt = 0; dt < 4; ++dt)
            og[row * 64 + dt * 16 + col] = f2bf(accO[dt][r]);
        if (col == 0) lg[row] = accL[r];
    }
}

// ---------------------------------------------------------------------------
// Combine: merge 4 splits, head-softmax mix, layernorm, FC. One wave per row.
// ---------------------------------------------------------------------------
__global__ __launch_bounds__(256) void combine_kernel(
    const unsigned short* __restrict__ Og, const float* __restrict__ Lg,
    const float* __restrict__ attn_w, const float* __restrict__ gamma,
    const float* __restrict__ beta, const float* __restrict__ fc_w,
    const float* __restrict__ fc_b, float* __restrict__ out)
{
    const int lane = threadIdx.x & 63;
    const int ty   = threadIdx.x >> 6;
    const int row  = blockIdx.x * 4 + ty;

    float a0 = attn_w[0], a1 = attn_w[1], a2 = attn_w[2], a3 = attn_w[3];
    float m = fmaxf(fmaxf(a0, a1), fmaxf(a2, a3));
    float e0 = __expf(a0 - m), e1 = __expf(a1 - m), e2 = __expf(a2 - m), e3 = __expf(a3 - m);
    float inv = 1.f / (e0 + e1 + e2 + e3);
    float aw[4] = {e0 * inv, e1 * inv, e2 * inv, e3 * inv};

    float c = 0.f;
    #pragma unroll
    for (int hh = 0; hh < NHEADS; ++hh) {
        float l = 0.f, o = 0.f;
        #pragma unroll
        for (int s = 0; s < NSPLIT; ++s) {
            l += Lg[(s * NHEADS + hh) * N_TOK + row];
            o += bf2f(Og[(size_t)((s * NHEADS + hh) * N_TOK + row) * 64 + lane]);
        }
        c += aw[hh] * o * __builtin_amdgcn_rcpf(l);
    }

    float s = c;
    #pragma unroll
    for (int off = 32; off > 0; off >>= 1) s += __shfl_xor(s, off);
    float mu = s * (1.f / 64.f);
    float d = c - mu;
    float v = d * d;
    #pragma unroll
    for (int off = 32; off > 0; off >>= 1) v += __shfl_xor(v, off);
    float normed = d * rsqrtf(v * (1.f / 64.f) + LN_EPS) * gamma[lane] + beta[lane];

    float lg[N_CLS];
    #pragma unroll
    for (int cc = 0; cc < N_CLS; ++cc) {
        float p = normed * fc_w[lane * N_CLS + cc];
        #pragma unroll
        for (int off = 32; off > 0; off >>= 1) p += __shfl_xor(p, off);
        lg[cc] = p;
    }
    if (lane == 0) {
        #pragma unroll
        for (int cc = 0; cc < N_CLS; ++cc)
            out[row * N_CLS + cc] = lg[cc] + fc_b[cc];
    }
}

// ---------------------------------------------------------------------------
extern "C" void kernel_launch(void* const* d_in, const int* in_sizes, int n_in,
                              void* d_out, int out_size, void* d_ws, size_t ws_size,
                              hipStream_t stream)
{
    const float* x      = (const float*)d_in[0];
    const float* proj_w = (const float*)d_in[1];
    const float* proj_b = (const float*)d_in[2];
    const float* head_w = (const float*)d_in[3];
    const float* head_b = (const float*)d_in[4];
    const float* attn_w = (const float*)d_in[5];
    const float* gamma  = (const float*)d_in[6];
    const float* beta   = (const float*)d_in[7];
    const float* fc_w   = (const float*)d_in[8];
    const float* fc_b   = (const float*)d_in[9];
    float* out = (float*)d_out;

    char* ws = (char*)d_ws;
    // ws layout (bytes):
    //   hp   bf16 [4][8192][64]        @ 0        (4 MB)
    //   Vf   bf16 [4][1024][64][8]     @ 4 MB     (4 MB, key-permuted)
    //   ssq2 f32  [4][8192]            @ 8 MB     (128 KB)
    //   Og   bf16 [4][4][8192][64]     @ 8M+128K  (16 MB)
    //   Lg   f32  [4][4][8192]         @ 24M+128K (512 KB)
    unsigned short* hp = (unsigned short*)(ws);
    unsigned short* Vf = (unsigned short*)(ws + (4u << 20));
    float* ssq2 = (float*)(ws + (8u << 20));
    unsigned short* Og = (unsigned short*)(ws + (8u << 20) + (128u << 10));
    float* Lg   = (float*)(ws + (24u << 20) + (128u << 10));

    stage1_kernel<<<N_TOK / 16, 256, 0, stream>>>(x, proj_w, proj_b, head_w, head_b,
                                                  hp, Vf, ssq2);
    dim3 g2(NHEADS * NSPLIT, N_TOK / 64);  // combo fastest -> spread over XCDs
    flash_kernel<<<g2, 256, 0, stream>>>(hp, Vf, ssq2, Og, Lg);
    combine_kernel<<<N_TOK / 4, 256, 0, stream>>>(Og, Lg, attn_w, gamma, beta,
                                                  fc_w, fc_b, out);
}

// Round 5
// 298.782 us; speedup vs baseline: 2.0243x; 1.4344x over previous
//
#include <hip/hip_runtime.h>

#define N_TOK 8192
#define D_IN 384
#define D_H 64
#define NHEADS 4
#define N_CLS 6
#define LN_EPS 1e-5f

typedef __attribute__((ext_vector_type(8))) short short8;
typedef __attribute__((ext_vector_type(4))) float f32x4;

#define L2E2 2.08136898100560774f   /* (log2 e)^2 */

__device__ __forceinline__ unsigned short f2bf(float f) {
    unsigned int u = __float_as_uint(f);
    u += 0x7FFFu + ((u >> 16) & 1u);          // RNE (finite values only here)
    return (unsigned short)(u >> 16);
}
__device__ __forceinline__ float bf2f(unsigned short s) {
    return __uint_as_float(((unsigned int)s) << 16);
}

// Permuted key position within a 64-key tile (pairs bf16 cols for packed LDS
// writes). P-columns and V-rows use the same bijection -> PV invariant.
__device__ __forceinline__ int kperm(int k) {
    return (k & 32) + 2 * (k & 15) + ((k >> 4) & 1);
}

// ---------------------------------------------------------------------------
// Stage 1: h = relu(x @ proj_w + proj_b); hp[h] = h @ head_w[h] + head_b[h]
// 4 rows per wave (weight loads reused x4 in registers).
// Outputs: hp bf16 [H][N][64] row-major, Vf bf16 key-grouped+permuted for PV
// B-frags, ssq2 fp32 [H][N] = (sum hp^2) * (log2 e)^2  (pre-scaled).
// ---------------------------------------------------------------------------
__global__ __launch_bounds__(256) void stage1_kernel(
    const float* __restrict__ x, const float* __restrict__ proj_w,
    const float* __restrict__ proj_b, const float* __restrict__ head_w,
    const float* __restrict__ head_b,
    unsigned short* __restrict__ hp, unsigned short* __restrict__ Vf,
    float* __restrict__ ssq2)
{
    const int lane = threadIdx.x & 63;
    const int ty   = threadIdx.x >> 6;
    const int rb   = blockIdx.x * 16 + ty * 4;   // 4 rows per wave

    __shared__ float h_sh[4][64][4];             // [wave][feature][row]

    float acc[4];
    {
        float b = proj_b[lane];
        #pragma unroll
        for (int r = 0; r < 4; ++r) acc[r] = b;
    }
    const float* x0 = x + (size_t)rb * D_IN;
    #pragma unroll 2
    for (int k4 = 0; k4 < D_IN / 4; ++k4) {
        float w0 = proj_w[(k4 * 4 + 0) * 64 + lane];
        float w1 = proj_w[(k4 * 4 + 1) * 64 + lane];
        float w2 = proj_w[(k4 * 4 + 2) * 64 + lane];
        float w3 = proj_w[(k4 * 4 + 3) * 64 + lane];
        #pragma unroll
        for (int r = 0; r < 4; ++r) {
            float4 xv = *(const float4*)(x0 + r * D_IN + k4 * 4); // wave-uniform
            acc[r] = fmaf(xv.x, w0, acc[r]);
            acc[r] = fmaf(xv.y, w1, acc[r]);
            acc[r] = fmaf(xv.z, w2, acc[r]);
            acc[r] = fmaf(xv.w, w3, acc[r]);
        }
    }
    #pragma unroll
    for (int r = 0; r < 4; ++r) h_sh[ty][lane][r] = fmaxf(acc[r], 0.f);
    // wave-private LDS segment; in-order DS pipe -> no barrier needed

    #pragma unroll
    for (int hh = 0; hh < NHEADS; ++hh) {
        float a[4];
        {
            float b = head_b[hh * 64 + lane];
            #pragma unroll
            for (int r = 0; r < 4; ++r) a[r] = b;
        }
        const float* wb = head_w + hh * 64 * 64;
        #pragma unroll 4
        for (int e = 0; e < 64; ++e) {
            float wv = wb[e * 64 + lane];
            float4 hv = *(const float4*)&h_sh[ty][e][0];   // uniform -> broadcast
            a[0] = fmaf(hv.x, wv, a[0]);
            a[1] = fmaf(hv.y, wv, a[1]);
            a[2] = fmaf(hv.z, wv, a[2]);
            a[3] = fmaf(hv.w, wv, a[3]);
        }
        #pragma unroll
        for (int r = 0; r < 4; ++r) {
            int row = rb + r;
            unsigned short hb = f2bf(a[r]);
            float hf = bf2f(hb);
            hp[(hh * N_TOK + row) * 64 + lane] = hb;
            int p = kperm(row & 63);
            Vf[((hh * (N_TOK / 8) + ((row >> 6) << 3) + (p >> 3)) * 64 + lane) * 8
               + (p & 7)] = hb;
            float s = hf * hf;
            #pragma unroll
            for (int off = 32; off > 0; off >>= 1) s += __shfl_xor(s, off);
            if (lane == 0) ssq2[hh * N_TOK + row] = s * L2E2;
        }
    }
}

// ---------------------------------------------------------------------------
// Flash distance-attention, 32 q-rows PER WAVE (two 16-row subtiles sharing
// every K/V byte loaded -> VMEM per unit work halved vs round 4, and two
// independent chains per iteration for ILP). Occupancy is register-limited
// (~3 waves/SIMD: acc regs accS32+accO32+accL8); rounds 2/4 proved extra
// grid waves don't help, so spend registers on reuse instead.
// Grid (4*nsplit combos, 64 q-tiles of 128 rows); combo = split*4+head so
// blockIdx.x%8 -> one head per XCD. Max logit is 0 (diagonal) -> no online
// rescaling. p = exp2(-sqrt(sq*(log2 e)^2)); partial O stored bf16.
// NO min-waves launch-bounds (round 3: (256,8) forced VGPR=32 -> spills).
// ---------------------------------------------------------------------------
__global__ __launch_bounds__(256) void flash_kernel(
    const unsigned short* __restrict__ hp, const unsigned short* __restrict__ Vf,
    const float* __restrict__ ssq2, unsigned short* __restrict__ Og,
    float* __restrict__ Lg, int kt_per_split)
{
    const int head  = blockIdx.x & 3;        // combo = split*NHEADS+head
    const int split = blockIdx.x >> 2;
    const int q0    = blockIdx.y * 128;      // 128 q-rows per block
    const int w     = threadIdx.x >> 6;
    const int lane  = threadIdx.x & 63;
    const int col   = lane & 15;
    const int quad  = lane >> 4;

    // Per-wave per-subtile P tile, 16 rows x 64 (permuted) cols, pitch 72.
    __shared__ __align__(16) unsigned short Psh[4][2][16][72];

    const unsigned short* hpH = hp + head * (N_TOK * 64);
    const unsigned short* VfH = Vf + head * (N_TOK * 64);
    const float* ssqH = ssq2 + head * N_TOK;

    const int rb = q0 + w * 32;              // this wave's 32 q-rows

    short8 aQ[2][2];
    float ssqn2[2][4];
    #pragma unroll
    for (int s = 0; s < 2; ++s) {
        const unsigned short* qrow = hpH + (rb + s * 16 + col) * 64;
        aQ[s][0] = *(const short8*)(qrow + quad * 8);
        aQ[s][1] = *(const short8*)(qrow + 32 + quad * 8);
        #pragma unroll
        for (int r = 0; r < 4; ++r)
            ssqn2[s][r] = ssqH[rb + s * 16 + quad * 4 + r];
    }

    const f32x4 zero4 = {0.f, 0.f, 0.f, 0.f};
    f32x4 accO[2][4] = {{zero4, zero4, zero4, zero4}, {zero4, zero4, zero4, zero4}};
    f32x4 accL[2] = {zero4, zero4};
    const short8 ones = {16256,16256,16256,16256,16256,16256,16256,16256}; // bf16 1.0
    const float NEG2L2 = -2.0f * L2E2;

    const int kt0 = split * kt_per_split;
    #pragma unroll 1
    for (int kt = kt0; kt < kt0 + kt_per_split; ++kt) {
        const unsigned short* kb = hpH + kt * 4096;
        const unsigned short* vb = VfH + kt * 4096;

        // key sum-squares (pre-scaled)
        float sm2[4];
        #pragma unroll
        for (int nt = 0; nt < 4; ++nt) sm2[nt] = ssqH[kt * 64 + nt * 16 + col];

        // V fragments: loaded ONCE, used by both subtiles' PV
        short8 bV[2][4];
        #pragma unroll
        for (int c = 0; c < 2; ++c)
            #pragma unroll
            for (int dt = 0; dt < 4; ++dt)
                bV[c][dt] = *(const short8*)(vb + ((c * 4 + quad) * 64 + dt * 16 + col) * 8);

        // ---- S = Q.K^T cross terms; each K frag feeds BOTH subtiles ----
        f32x4 accS[2][4] = {{zero4, zero4, zero4, zero4}, {zero4, zero4, zero4, zero4}};
        #pragma unroll
        for (int nt = 0; nt < 4; ++nt) {
            const unsigned short* kr = kb + (nt * 16 + col) * 64 + quad * 8;
            short8 b0 = *(const short8*)kr;
            short8 b1 = *(const short8*)(kr + 32);
            accS[0][nt] = __builtin_amdgcn_mfma_f32_16x16x32_bf16(aQ[0][0], b0, accS[0][nt], 0, 0, 0);
            accS[0][nt] = __builtin_amdgcn_mfma_f32_16x16x32_bf16(aQ[0][1], b1, accS[0][nt], 0, 0, 0);
            accS[1][nt] = __builtin_amdgcn_mfma_f32_16x16x32_bf16(aQ[1][0], b0, accS[1][nt], 0, 0, 0);
            accS[1][nt] = __builtin_amdgcn_mfma_f32_16x16x32_bf16(aQ[1][1], b1, accS[1][nt], 0, 0, 0);
        }

        // ---- p = exp2(-sqrt(max(sq',0))); pack bf16 pairs; 16 ds_write_b32 ----
        #pragma unroll
        for (int s = 0; s < 2; ++s) {
            float pf[4][4];
            #pragma unroll
            for (int nt = 0; nt < 4; ++nt)
                #pragma unroll
                for (int r = 0; r < 4; ++r) {
                    float sq = fmaf(accS[s][nt][r], NEG2L2, ssqn2[s][r] + sm2[nt]);
                    float d2 = __builtin_amdgcn_sqrtf(fmaxf(sq, 0.f));
                    pf[nt][r] = __builtin_amdgcn_exp2f(-d2);
                }
            #pragma unroll
            for (int r = 0; r < 4; ++r) {
                unsigned int d0 = __builtin_amdgcn_perm(__float_as_uint(pf[1][r]),
                                                        __float_as_uint(pf[0][r]), 0x07060302u);
                unsigned int d1 = __builtin_amdgcn_perm(__float_as_uint(pf[3][r]),
                                                        __float_as_uint(pf[2][r]), 0x07060302u);
                int rr = quad * 4 + r;
                *(unsigned int*)&Psh[w][s][rr][2 * col]      = d0;
                *(unsigned int*)&Psh[w][s][rr][32 + 2 * col] = d1;
            }
            // diag tile: force p=1.0 exactly (wave-uniform predicate, 1/32 tiles)
            int r0 = rb + s * 16;
            if (kt == (r0 >> 6) && lane < 16) {
                int t = (r0 >> 4) & 3;
                Psh[w][s][lane][((t & 2) << 4) + 2 * lane + (t & 1)] = 0x3F80;
            }
        }

        // ---- PV: O += P.V, l += rowsum(P). Wave-private LDS, no barrier ----
        #pragma unroll
        for (int c = 0; c < 2; ++c) {
            short8 aP0 = *(const short8*)&Psh[w][0][col][c * 32 + quad * 8];
            short8 aP1 = *(const short8*)&Psh[w][1][col][c * 32 + quad * 8];
            accL[0] = __builtin_amdgcn_mfma_f32_16x16x32_bf16(aP0, ones, accL[0], 0, 0, 0);
            accL[1] = __builtin_amdgcn_mfma_f32_16x16x32_bf16(aP1, ones, accL[1], 0, 0, 0);
            #pragma unroll
            for (int dt = 0; dt < 4; ++dt) {
                accO[0][dt] = __builtin_amdgcn_mfma_f32_16x16x32_bf16(aP0, bV[c][dt], accO[0][dt], 0, 0, 0);
                accO[1][dt] = __builtin_amdgcn_mfma_f32_16x16x32_bf16(aP1, bV[c][dt], accO[1][dt], 0, 0, 0);
            }
        }
    }

    // ---- epilogue: unnormalized O (bf16) and l (f32) for this split ----
    unsigned short* og = Og + (size_t)(split * NHEADS + head) * N_TOK * 64;
    float* lg = Lg + (size_t)(split * NHEADS + head) * N_TOK;
    #pragma unroll
    for (int s = 0; s < 2; ++s)
        #pragma unroll
        for (int r = 0; r < 4; ++r) {
            int row = rb + s * 16 + quad * 4 + r;
            #pragma unroll
            for (int dt = 0; dt < 4; ++dt)
                og[row * 64 + dt * 16 + col] = f2bf(accO[s][dt][r]);
            if (col == 0) lg[row] = accL[s][r];
        }
}

// ---------------------------------------------------------------------------
// Combine: merge nsplit splits, head-softmax mix, layernorm, FC. Wave per row.
// ---------------------------------------------------------------------------
__global__ __launch_bounds__(256) void combine_kernel(
    const unsigned short* __restrict__ Og, const float* __restrict__ Lg,
    const float* __restrict__ attn_w, const float* __restrict__ gamma,
    const float* __restrict__ beta, const float* __restrict__ fc_w,
    const float* __restrict__ fc_b, float* __restrict__ out, int nsplit)
{
    const int lane = threadIdx.x & 63;
    const int ty   = threadIdx.x >> 6;
    const int row  = blockIdx.x * 4 + ty;

    float a0 = attn_w[0], a1 = attn_w[1], a2 = attn_w[2], a3 = attn_w[3];
    float m = fmaxf(fmaxf(a0, a1), fmaxf(a2, a3));
    float e0 = __expf(a0 - m), e1 = __expf(a1 - m), e2 = __expf(a2 - m), e3 = __expf(a3 - m);
    float inv = 1.f / (e0 + e1 + e2 + e3);
    float aw[4] = {e0 * inv, e1 * inv, e2 * inv, e3 * inv};

    float c = 0.f;
    #pragma unroll
    for (int hh = 0; hh < NHEADS; ++hh) {
        float l = 0.f, o = 0.f;
        for (int s = 0; s < nsplit; ++s) {
            l += Lg[(s * NHEADS + hh) * N_TOK + row];
            o += bf2f(Og[(size_t)((s * NHEADS + hh) * N_TOK + row) * 64 + lane]);
        }
        c += aw[hh] * o * __builtin_amdgcn_rcpf(l);
    }

    float s = c;
    #pragma unroll
    for (int off = 32; off > 0; off >>= 1) s += __shfl_xor(s, off);
    float mu = s * (1.f / 64.f);
    float d = c - mu;
    float v = d * d;
    #pragma unroll
    for (int off = 32; off > 0; off >>= 1) v += __shfl_xor(v, off);
    float normed = d * rsqrtf(v * (1.f / 64.f) + LN_EPS) * gamma[lane] + beta[lane];

    float lg[N_CLS];
    #pragma unroll
    for (int cc = 0; cc < N_CLS; ++cc) {
        float p = normed * fc_w[lane * N_CLS + cc];
        #pragma unroll
        for (int off = 32; off > 0; off >>= 1) p += __shfl_xor(p, off);
        lg[cc] = p;
    }
    if (lane == 0) {
        #pragma unroll
        for (int cc = 0; cc < N_CLS; ++cc)
            out[row * N_CLS + cc] = lg[cc] + fc_b[cc];
    }
}

// ---------------------------------------------------------------------------
extern "C" void kernel_launch(void* const* d_in, const int* in_sizes, int n_in,
                              void* d_out, int out_size, void* d_ws, size_t ws_size,
                              hipStream_t stream)
{
    const float* x      = (const float*)d_in[0];
    const float* proj_w = (const float*)d_in[1];
    const float* proj_b = (const float*)d_in[2];
    const float* head_w = (const float*)d_in[3];
    const float* head_b = (const float*)d_in[4];
    const float* attn_w = (const float*)d_in[5];
    const float* gamma  = (const float*)d_in[6];
    const float* beta   = (const float*)d_in[7];
    const float* fc_w   = (const float*)d_in[8];
    const float* fc_b   = (const float*)d_in[9];
    float* out = (float*)d_out;

    char* ws = (char*)d_ws;
    // ws layout (bytes):
    //   hp   bf16 [4][8192][64]          @ 0        (4 MB)
    //   Vf   bf16 [4][1024][64][8]       @ 4 MB     (4 MB, key-permuted)
    //   ssq2 f32  [4][8192]              @ 8 MB     (128 KB)
    //   Og   bf16 [nsplit][4][8192][64]  @ 8M+128K  (16/32 MB)
    //   Lg   f32  [nsplit][4][8192]      after Og   (0.5/1 MB)
    unsigned short* hp = (unsigned short*)(ws);
    unsigned short* Vf = (unsigned short*)(ws + (4u << 20));
    float* ssq2 = (float*)(ws + (8u << 20));
    unsigned short* Og = (unsigned short*)(ws + (8u << 20) + (128u << 10));

    // nsplit=8 wants ~41.2 MB of ws; fall back to 4 (proven fit) otherwise.
    size_t base = (8u << 20) + (128u << 10);
    size_t need8 = base + (size_t)8 * NHEADS * N_TOK * (64 * 2 + 4);
    int nsplit = (ws_size >= need8) ? 8 : 4;
    float* Lg = (float*)(ws + base + (size_t)nsplit * NHEADS * N_TOK * 64 * 2);

    stage1_kernel<<<N_TOK / 16, 256, 0, stream>>>(x, proj_w, proj_b, head_w, head_b,
                                                  hp, Vf, ssq2);
    dim3 g2(NHEADS * nsplit, N_TOK / 128);  // combo fastest -> one head per XCD
    flash_kernel<<<g2, 256, 0, stream>>>(hp, Vf, ssq2, Og, Lg,
                                         (N_TOK / 64) / nsplit);
    combine_kernel<<<N_TOK / 4, 256, 0, stream>>>(Og, Lg, attn_w, gamma, beta,
                                                  fc_w, fc_b, out, nsplit);
}

// Round 6
// 295.441 us; speedup vs baseline: 2.0472x; 1.0113x over previous
//
#include <hip/hip_runtime.h>

#define N_TOK 8192
#define D_IN 384
#define D_H 64
#define NHEADS 4
#define NSPLIT 4
#define N_CLS 6
#define LN_EPS 1e-5f

typedef __attribute__((ext_vector_type(8))) short short8;
typedef __attribute__((ext_vector_type(4))) float f32x4;

#define L2E2 2.08136898100560774f   /* (log2 e)^2 */

__device__ __forceinline__ unsigned short f2bf(float f) {
    unsigned int u = __float_as_uint(f);
    u += 0x7FFFu + ((u >> 16) & 1u);          // RNE (finite values only here)
    return (unsigned short)(u >> 16);
}
__device__ __forceinline__ float bf2f(unsigned short s) {
    return __uint_as_float(((unsigned int)s) << 16);
}

// Permuted key position within a 64-key tile (pairs bf16 cols for packed LDS
// writes in flash). P-columns and V-rows share the bijection -> PV invariant.
__device__ __forceinline__ int kperm(int k) {
    return (k & 32) + 2 * (k & 15) + ((k >> 4) & 1);
}

// ---------------------------------------------------------------------------
// Stage 1a: h = relu(x @ proj_w + proj_b), f32 coalesced out. 4 rows/wave.
// ---------------------------------------------------------------------------
__global__ __launch_bounds__(256) void stage1a_kernel(
    const float* __restrict__ x, const float* __restrict__ proj_w,
    const float* __restrict__ proj_b, float* __restrict__ h)
{
    const int lane = threadIdx.x & 63;
    const int ty   = threadIdx.x >> 6;
    const int rb   = blockIdx.x * 16 + ty * 4;

    float acc[4];
    {
        float b = proj_b[lane];
        #pragma unroll
        for (int r = 0; r < 4; ++r) acc[r] = b;
    }
    const float* x0 = x + (size_t)rb * D_IN;
    #pragma unroll 2
    for (int k4 = 0; k4 < D_IN / 4; ++k4) {
        float w0 = proj_w[(k4 * 4 + 0) * 64 + lane];
        float w1 = proj_w[(k4 * 4 + 1) * 64 + lane];
        float w2 = proj_w[(k4 * 4 + 2) * 64 + lane];
        float w3 = proj_w[(k4 * 4 + 3) * 64 + lane];
        #pragma unroll
        for (int r = 0; r < 4; ++r) {
            float4 xv = *(const float4*)(x0 + r * D_IN + k4 * 4); // wave-uniform
            acc[r] = fmaf(xv.x, w0, acc[r]);
            acc[r] = fmaf(xv.y, w1, acc[r]);
            acc[r] = fmaf(xv.z, w2, acc[r]);
            acc[r] = fmaf(xv.w, w3, acc[r]);
        }
    }
    #pragma unroll
    for (int r = 0; r < 4; ++r)
        h[(size_t)(rb + r) * 64 + lane] = fmaxf(acc[r], 0.f);
}

// ---------------------------------------------------------------------------
// Stage 1b: per (64-row block, head): hp = h @ head_w[head] + head_b[head].
// Grid (N/64, NHEADS). h tile staged transposed in LDS for broadcast reads.
// Outputs: hp bf16 coalesced; Vf bf16 key-permuted, built in LDS and written
// COALESCED b128 (round<=5 wrote Vf as per-lane b16 scatter at stride 16B);
// ssq2 = (sum hp^2)*(log2 e)^2.
// ---------------------------------------------------------------------------
__global__ __launch_bounds__(256) void stage1b_kernel(
    const float* __restrict__ h, const float* __restrict__ head_w,
    const float* __restrict__ head_b,
    unsigned short* __restrict__ hp, unsigned short* __restrict__ Vf,
    float* __restrict__ ssq2)
{
    const int lane = threadIdx.x & 63;
    const int ty   = threadIdx.x >> 6;
    const int rb0  = blockIdx.x * 64;
    const int head = blockIdx.y;

    __shared__ float hT[64][65];                        // [feature][row]
    __shared__ __align__(16) unsigned short vt[8][64][8]; // [kg][d][j] permuted

    // ---- stage h tile (64 rows x 64 feat) transposed into LDS ----
    {
        int r  = threadIdx.x >> 2;
        int c0 = (threadIdx.x & 3) * 16;
        const float* hr = h + (size_t)(rb0 + r) * 64 + c0;
        #pragma unroll
        for (int j4 = 0; j4 < 4; ++j4) {
            float4 v = *(const float4*)(hr + j4 * 4);
            hT[c0 + j4 * 4 + 0][r] = v.x;
            hT[c0 + j4 * 4 + 1][r] = v.y;
            hT[c0 + j4 * 4 + 2][r] = v.z;
            hT[c0 + j4 * 4 + 3][r] = v.w;
        }
    }
    __syncthreads();

    // ---- hp = h @ W + b for this wave's 16 rows (lane = output dim) ----
    float a[16];
    {
        float b = head_b[head * 64 + lane];
        #pragma unroll
        for (int r = 0; r < 16; ++r) a[r] = b;
    }
    const float* wb = head_w + head * 64 * 64;
    #pragma unroll 4
    for (int e = 0; e < 64; ++e) {
        float wv = wb[e * 64 + lane];
        #pragma unroll
        for (int g = 0; g < 4; ++g) {
            float4 hv = *(const float4*)&hT[e][ty * 16 + g * 4];
            a[g * 4 + 0] = fmaf(hv.x, wv, a[g * 4 + 0]);
            a[g * 4 + 1] = fmaf(hv.y, wv, a[g * 4 + 1]);
            a[g * 4 + 2] = fmaf(hv.z, wv, a[g * 4 + 2]);
            a[g * 4 + 3] = fmaf(hv.w, wv, a[g * 4 + 3]);
        }
    }

    // ---- round, store hp (coalesced), vt (permuted, LDS), ssq2 ----
    #pragma unroll
    for (int r = 0; r < 16; ++r) {
        int kl  = ty * 16 + r;                // key within 64-tile
        int row = rb0 + kl;
        unsigned short hb = f2bf(a[r]);
        float hf = bf2f(hb);
        hp[((size_t)head * N_TOK + row) * 64 + lane] = hb;
        int p = kperm(kl);
        vt[p >> 3][lane][p & 7] = hb;
        float s = hf * hf;
        #pragma unroll
        for (int off = 32; off > 0; off >>= 1) s += __shfl_xor(s, off);
        if (lane == 0) ssq2[head * N_TOK + row] = s * L2E2;
    }
    __syncthreads();

    // ---- write Vf coalesced: 512 chunks of 16B, 2 per thread ----
    #pragma unroll
    for (int i = 0; i < 2; ++i) {
        int c  = threadIdx.x + 256 * i;
        int kg = c >> 6, d = c & 63;
        short8 v = *(const short8*)&vt[kg][d][0];
        *(short8*)&Vf[(((size_t)head * (N_TOK / 8) + blockIdx.x * 8 + kg) * 64 + d) * 8] = v;
    }
}

// ---------------------------------------------------------------------------
// Flash distance-attention, 32 q-rows per wave (two 16-row subtiles sharing
// all K/V bytes). bV loads moved into the PV phase so they are not live
// across QK+softmax (round-5 held bV(32 VGPR) alongside accS(32): peak ~148
// -> 3 waves/SIMD; now peak ~120 -> target 4 waves/SIMD for latency cover).
// Grid (16 combos, 64 q-blocks of 128 rows); combo = split*4+head so
// blockIdx.x%8 -> one head per XCD. Max logit is 0 (diagonal) -> no online
// rescaling. p = exp2(-sqrt(sq*(log2 e)^2)); partial O stored bf16.
// NO min-waves launch-bounds (round 3: (256,8) forced VGPR=32 -> spills).
// ---------------------------------------------------------------------------
__global__ __launch_bounds__(256) void flash_kernel(
    const unsigned short* __restrict__ hp, const unsigned short* __restrict__ Vf,
    const float* __restrict__ ssq2, unsigned short* __restrict__ Og,
    float* __restrict__ Lg)
{
    const int head  = blockIdx.x & 3;        // combo = split*NHEADS+head
    const int split = blockIdx.x >> 2;
    const int q0    = blockIdx.y * 128;      // 128 q-rows per block
    const int w     = threadIdx.x >> 6;
    const int lane  = threadIdx.x & 63;
    const int col   = lane & 15;
    const int quad  = lane >> 4;

    __shared__ __align__(16) unsigned short Psh[4][2][16][72];

    const unsigned short* hpH = hp + head * (N_TOK * 64);
    const unsigned short* VfH = Vf + head * (N_TOK * 64);
    const float* ssqH = ssq2 + head * N_TOK;

    const int rb = q0 + w * 32;              // this wave's 32 q-rows

    short8 aQ[2][2];
    float ssqn2[2][4];
    #pragma unroll
    for (int s = 0; s < 2; ++s) {
        const unsigned short* qrow = hpH + (rb + s * 16 + col) * 64;
        aQ[s][0] = *(const short8*)(qrow + quad * 8);
        aQ[s][1] = *(const short8*)(qrow + 32 + quad * 8);
        #pragma unroll
        for (int r = 0; r < 4; ++r)
            ssqn2[s][r] = ssqH[rb + s * 16 + quad * 4 + r];
    }

    const f32x4 zero4 = {0.f, 0.f, 0.f, 0.f};
    f32x4 accO[2][4] = {{zero4, zero4, zero4, zero4}, {zero4, zero4, zero4, zero4}};
    f32x4 accL[2] = {zero4, zero4};
    const short8 ones = {16256,16256,16256,16256,16256,16256,16256,16256}; // bf16 1.0
    const float NEG2L2 = -2.0f * L2E2;

    const int kt0 = split * (N_TOK / 64 / NSPLIT);
    #pragma unroll 1
    for (int kt = kt0; kt < kt0 + N_TOK / 64 / NSPLIT; ++kt) {
        const unsigned short* kb = hpH + kt * 4096;
        const unsigned short* vb = VfH + kt * 4096;

        float sm2[4];
        #pragma unroll
        for (int nt = 0; nt < 4; ++nt) sm2[nt] = ssqH[kt * 64 + nt * 16 + col];

        // ---- S = Q.K^T cross terms; each K frag feeds BOTH subtiles ----
        f32x4 accS[2][4] = {{zero4, zero4, zero4, zero4}, {zero4, zero4, zero4, zero4}};
        #pragma unroll
        for (int nt = 0; nt < 4; ++nt) {
            const unsigned short* kr = kb + (nt * 16 + col) * 64 + quad * 8;
            short8 b0 = *(const short8*)kr;
            short8 b1 = *(const short8*)(kr + 32);
            accS[0][nt] = __builtin_amdgcn_mfma_f32_16x16x32_bf16(aQ[0][0], b0, accS[0][nt], 0, 0, 0);
            accS[0][nt] = __builtin_amdgcn_mfma_f32_16x16x32_bf16(aQ[0][1], b1, accS[0][nt], 0, 0, 0);
            accS[1][nt] = __builtin_amdgcn_mfma_f32_16x16x32_bf16(aQ[1][0], b0, accS[1][nt], 0, 0, 0);
            accS[1][nt] = __builtin_amdgcn_mfma_f32_16x16x32_bf16(aQ[1][1], b1, accS[1][nt], 0, 0, 0);
        }

        // ---- p = exp2(-sqrt(max(sq',0))); pack bf16 pairs; 16 ds_write_b32 ----
        #pragma unroll
        for (int s = 0; s < 2; ++s) {
            float pf[4][4];
            #pragma unroll
            for (int nt = 0; nt < 4; ++nt)
                #pragma unroll
                for (int r = 0; r < 4; ++r) {
                    float sq = fmaf(accS[s][nt][r], NEG2L2, ssqn2[s][r] + sm2[nt]);
                    float d2 = __builtin_amdgcn_sqrtf(fmaxf(sq, 0.f));
                    pf[nt][r] = __builtin_amdgcn_exp2f(-d2);
                }
            #pragma unroll
            for (int r = 0; r < 4; ++r) {
                unsigned int d0 = __builtin_amdgcn_perm(__float_as_uint(pf[1][r]),
                                                        __float_as_uint(pf[0][r]), 0x07060302u);
                unsigned int d1 = __builtin_amdgcn_perm(__float_as_uint(pf[3][r]),
                                                        __float_as_uint(pf[2][r]), 0x07060302u);
                int rr = quad * 4 + r;
                *(unsigned int*)&Psh[w][s][rr][2 * col]      = d0;
                *(unsigned int*)&Psh[w][s][rr][32 + 2 * col] = d1;
            }
            int r0 = rb + s * 16;
            if (kt == (r0 >> 6) && lane < 16) {
                int t = (r0 >> 4) & 3;
                Psh[w][s][lane][((t & 2) << 4) + 2 * lane + (t & 1)] = 0x3F80;
            }
        }

        // ---- PV: O += P.V, l += rowsum(P). bV loaded HERE (accS dead) ----
        #pragma unroll
        for (int c = 0; c < 2; ++c) {
            short8 bV[4];
            #pragma unroll
            for (int dt = 0; dt < 4; ++dt)
                bV[dt] = *(const short8*)(vb + ((c * 4 + quad) * 64 + dt * 16 + col) * 8);
            short8 aP0 = *(const short8*)&Psh[w][0][col][c * 32 + quad * 8];
            short8 aP1 = *(const short8*)&Psh[w][1][col][c * 32 + quad * 8];
            accL[0] = __builtin_amdgcn_mfma_f32_16x16x32_bf16(aP0, ones, accL[0], 0, 0, 0);
            accL[1] = __builtin_amdgcn_mfma_f32_16x16x32_bf16(aP1, ones, accL[1], 0, 0, 0);
            #pragma unroll
            for (int dt = 0; dt < 4; ++dt) {
                accO[0][dt] = __builtin_amdgcn_mfma_f32_16x16x32_bf16(aP0, bV[dt], accO[0][dt], 0, 0, 0);
                accO[1][dt] = __builtin_amdgcn_mfma_f32_16x16x32_bf16(aP1, bV[dt], accO[1][dt], 0, 0, 0);
            }
        }
    }

    // ---- epilogue: unnormalized O (bf16) and l (f32) for this split ----
    unsigned short* og = Og + (size_t)(split * NHEADS + head) * N_TOK * 64;
    float* lg = Lg + (size_t)(split * NHEADS + head) * N_TOK;
    #pragma unroll
    for (int s = 0; s < 2; ++s)
        #pragma unroll
        for (int r = 0; r < 4; ++r) {
            int row = rb + s * 16 + quad * 4 + r;
            #pragma unroll
            for (int dt = 0; dt < 4; ++dt)
                og[row * 64 + dt * 16 + col] = f2bf(accO[s][dt][r]);
            if (col == 0) lg[row] = accL[s][r];
        }
}

// ---------------------------------------------------------------------------
// Combine: merge NSPLIT splits, head-softmax mix, layernorm, FC. Wave per row.
// ---------------------------------------------------------------------------
__global__ __launch_bounds__(256) void combine_kernel(
    const unsigned short* __restrict__ Og, const float* __restrict__ Lg,
    const float* __restrict__ attn_w, const float* __restrict__ gamma,
    const float* __restrict__ beta, const float* __restrict__ fc_w,
    const float* __restrict__ fc_b, float* __restrict__ out)
{
    const int lane = threadIdx.x & 63;
    const int ty   = threadIdx.x >> 6;
    const int row  = blockIdx.x * 4 + ty;

    float a0 = attn_w[0], a1 = attn_w[1], a2 = attn_w[2], a3 = attn_w[3];
    float m = fmaxf(fmaxf(a0, a1), fmaxf(a2, a3));
    float e0 = __expf(a0 - m), e1 = __expf(a1 - m), e2 = __expf(a2 - m), e3 = __expf(a3 - m);
    float inv = 1.f / (e0 + e1 + e2 + e3);
    float aw[4] = {e0 * inv, e1 * inv, e2 * inv, e3 * inv};

    float c = 0.f;
    #pragma unroll
    for (int hh = 0; hh < NHEADS; ++hh) {
        float l = 0.f, o = 0.f;
        #pragma unroll
        for (int s = 0; s < NSPLIT; ++s) {
            l += Lg[(s * NHEADS + hh) * N_TOK + row];
            o += bf2f(Og[(size_t)((s * NHEADS + hh) * N_TOK + row) * 64 + lane]);
        }
        c += aw[hh] * o * __builtin_amdgcn_rcpf(l);
    }

    float s = c;
    #pragma unroll
    for (int off = 32; off > 0; off >>= 1) s += __shfl_xor(s, off);
    float mu = s * (1.f / 64.f);
    float d = c - mu;
    float v = d * d;
    #pragma unroll
    for (int off = 32; off > 0; off >>= 1) v += __shfl_xor(v, off);
    float normed = d * rsqrtf(v * (1.f / 64.f) + LN_EPS) * gamma[lane] + beta[lane];

    float lg[N_CLS];
    #pragma unroll
    for (int cc = 0; cc < N_CLS; ++cc) {
        float p = normed * fc_w[lane * N_CLS + cc];
        #pragma unroll
        for (int off = 32; off > 0; off >>= 1) p += __shfl_xor(p, off);
        lg[cc] = p;
    }
    if (lane == 0) {
        #pragma unroll
        for (int cc = 0; cc < N_CLS; ++cc)
            out[row * N_CLS + cc] = lg[cc] + fc_b[cc];
    }
}

// ---------------------------------------------------------------------------
extern "C" void kernel_launch(void* const* d_in, const int* in_sizes, int n_in,
                              void* d_out, int out_size, void* d_ws, size_t ws_size,
                              hipStream_t stream)
{
    const float* x      = (const float*)d_in[0];
    const float* proj_w = (const float*)d_in[1];
    const float* proj_b = (const float*)d_in[2];
    const float* head_w = (const float*)d_in[3];
    const float* head_b = (const float*)d_in[4];
    const float* attn_w = (const float*)d_in[5];
    const float* gamma  = (const float*)d_in[6];
    const float* beta   = (const float*)d_in[7];
    const float* fc_w   = (const float*)d_in[8];
    const float* fc_b   = (const float*)d_in[9];
    float* out = (float*)d_out;

    char* ws = (char*)d_ws;
    // ws layout (bytes):
    //   hp   bf16 [4][8192][64]          @ 0          (4 MB)
    //   Vf   bf16 [4][1024][64][8]       @ 4 MB       (4 MB, key-permuted)
    //   ssq2 f32  [4][8192]              @ 8 MB       (128 KB)
    //   h    f32  [8192][64]             @ 8M+128K    (2 MB)
    //   Og   bf16 [4][4][8192][64]       @ 10M+128K   (16 MB)
    //   Lg   f32  [4][4][8192]           @ 26M+128K   (512 KB)
    unsigned short* hp = (unsigned short*)(ws);
    unsigned short* Vf = (unsigned short*)(ws + (4u << 20));
    float* ssq2 = (float*)(ws + (8u << 20));
    float* h    = (float*)(ws + (8u << 20) + (128u << 10));
    unsigned short* Og = (unsigned short*)(ws + (10u << 20) + (128u << 10));
    float* Lg   = (float*)(ws + (26u << 20) + (128u << 10));

    stage1a_kernel<<<N_TOK / 16, 256, 0, stream>>>(x, proj_w, proj_b, h);
    dim3 g1b(N_TOK / 64, NHEADS);
    stage1b_kernel<<<g1b, 256, 0, stream>>>(h, head_w, head_b, hp, Vf, ssq2);
    dim3 g2(NHEADS * NSPLIT, N_TOK / 128);  // combo fastest -> one head per XCD
    flash_kernel<<<g2, 256, 0, stream>>>(hp, Vf, ssq2, Og, Lg);
    combine_kernel<<<N_TOK / 4, 256, 0, stream>>>(Og, Lg, attn_w, gamma, beta,
                                                  fc_w, fc_b, out);
}